// Round 5
// baseline (574.892 us; speedup 1.0000x reference)
//
#include <hip/hip_runtime.h>
#include <hip/hip_bf16.h>

typedef short short8 __attribute__((ext_vector_type(8)));
typedef float f32x4 __attribute__((ext_vector_type(4)));

using bf16 = __hip_bfloat16;

#define MFMA16(a, b, c) __builtin_amdgcn_mfma_f32_16x16x32_bf16((a), (b), (c), 0, 0, 0)

__device__ __forceinline__ short8 ldb8(const bf16* p) {
    return *reinterpret_cast<const short8*>(p);
}
__device__ __forceinline__ unsigned int bfu(float f) {   // exact small ints -> bf16 bits
    union { float f; unsigned int u; } x{f};
    return x.u >> 16;
}

// -------------------------------------------------------------------------
__global__ __launch_bounds__(256) void k_cast(const float* __restrict__ src,
                                              bf16* __restrict__ dst, int n)
{
    for (int i = blockIdx.x * 256 + threadIdx.x; i < n; i += gridDim.x * 256)
        dst[i] = __float2bfloat16(src[i]);
}

// -------------------------------------------------------------------------
// Kernel 1: QKV projection f32 — ROUND-2 VERBATIM (measured 130 us; full
// occupancy: VGPR 36, 1536 blocks). 64x64 tile, 4x4/thread, BK=16.
// -------------------------------------------------------------------------
__global__ __launch_bounds__(256) void k_qkv_f32(
    const float* __restrict__ X, const float* __restrict__ W, const float* __restrict__ bq,
    const float* __restrict__ qvm, const float* __restrict__ kvm, const float* __restrict__ vvm,
    const int* __restrict__ qac, const int* __restrict__ kac, const int* __restrict__ vac,
    bf16* __restrict__ Q2, bf16* __restrict__ K2c, bf16* __restrict__ VsT, bf16* __restrict__ VaT)
{
    __shared__ float As[16][68];
    __shared__ float Bs[16][68];
    const int tid = threadIdx.x;
    const int r0 = blockIdx.y * 64;
    const int c0 = blockIdx.x * 64;
    const int lr = tid & 63, lk4 = (tid >> 6) * 4;
    const int tm = (tid & 15) * 4, tn = (tid >> 4) * 4;

    float acc[4][4] = {};
    for (int kk = 0; kk < 512; kk += 16) {
        const float4 a4 = *reinterpret_cast<const float4*>(X + (size_t)(r0 + lr) * 512 + kk + lk4);
        const float4 b4 = *reinterpret_cast<const float4*>(W + (size_t)(c0 + lr) * 512 + kk + lk4);
        __syncthreads();
        As[lk4 + 0][lr] = a4.x; As[lk4 + 1][lr] = a4.y; As[lk4 + 2][lr] = a4.z; As[lk4 + 3][lr] = a4.w;
        Bs[lk4 + 0][lr] = b4.x; Bs[lk4 + 1][lr] = b4.y; Bs[lk4 + 2][lr] = b4.z; Bs[lk4 + 3][lr] = b4.w;
        __syncthreads();
        #pragma unroll
        for (int k = 0; k < 16; ++k) {
            const float4 av = *reinterpret_cast<const float4*>(&As[k][tm]);
            const float4 bv = *reinterpret_cast<const float4*>(&Bs[k][tn]);
            const float ar[4] = {av.x, av.y, av.z, av.w};
            const float br[4] = {bv.x, bv.y, bv.z, bv.w};
            #pragma unroll
            for (int i = 0; i < 4; ++i)
                #pragma unroll
                for (int j = 0; j < 4; ++j)
                    acc[i][j] += ar[i] * br[j];
        }
    }

    const int sel = c0 >> 9;
    const int h   = (c0 & 511) >> 6;
    #pragma unroll
    for (int j = 0; j < 4; ++j) {
        const int col = c0 + tn + j;
        const int d = col & 63;
        const float bcol = bq[col];
        #pragma unroll
        for (int i = 0; i < 4; ++i) {
            const int row = r0 + tm + i;
            const int b = row >> 10, n = row & 1023;
            const int bh = b * 8 + h;
            const size_t i4 = ((size_t)(bh * 1024 + n)) * 64 + d;
            const float val = acc[i][j] + bcol;
            float vm; int a0i;
            if (sel == 0)      { vm = qvm[i4]; a0i = qac[i4]; }
            else if (sel == 1) { vm = kvm[i4]; a0i = kac[i4]; }
            else               { vm = vvm[i4]; a0i = vac[i4]; }
            const float v_ = vm + val;
            int sp = ((v_ >= 1.0f) && (a0i < 7)) ? 1 : 0;
            if ((v_ < 0.0f) && (a0i > -8)) sp -= 1;
            if (sel == 0) {
                const size_t qi = ((size_t)(bh * 1024 + n)) * 128 + d;
                Q2[qi]      = __float2bfloat16((float)(a0i + sp));
                Q2[qi + 64] = __float2bfloat16((float)sp);
            } else if (sel == 1) {
                const size_t ki = ((size_t)(bh * 1024 + n)) * 128 + d;
                K2c[ki]      = __float2bfloat16((float)sp);
                K2c[ki + 64] = __float2bfloat16((float)a0i);
            } else {
                const size_t vi = ((size_t)(bh * 64 + d)) * 1024 + n;
                VsT[vi] = __float2bfloat16((float)sp);
                VaT[vi] = __float2bfloat16((float)a0i);
            }
        }
    }
}

// -------------------------------------------------------------------------
// Kernel 2 (fused): scores MFMA -> S as i16 (exact, 33 KB -> 4 blocks/CU)
// -> softmax (identical column order + shuffle tree => bit-identical sum)
// -> attn IF (e recomputed from i16; identical expf input) -> P1 pass (Vs)
// -> P2 pass (Va) with P overlaying the same 33 KB LDS -> after-IF -> O2.
// Row stride = 520 dwords (1040 i16): phase-2 strided reads conflict-free.
// -------------------------------------------------------------------------
__global__ __launch_bounds__(256, 4) void k_attn(
    const bf16* __restrict__ Q2, const bf16* __restrict__ K2c,
    const float* __restrict__ avm, const int* __restrict__ aac,
    const bf16* __restrict__ VsT, const bf16* __restrict__ VaT,
    bf16* __restrict__ O2)
{
    __shared__ unsigned Sdw[16 * 520];           // 33280 B, S(i16) then P overlay
    char* const Sc = (char*)Sdw;
    const int tid = threadIdx.x;
    const int w = tid >> 6, lane = tid & 63;
    const int lo = lane & 15, hi = lane >> 4;
    const int h = blockIdx.y, bb = blockIdx.z;
    const int bh = bb * 8 + h;
    const int n0 = blockIdx.x * 16;

    // ---- Phase 1: scores -> S16 (raw exact ints; scale 0.125 applied at exp) ----
    {
        const bf16* qb = Q2 + ((size_t)(bh * 1024 + n0 + lo)) * 128 + hi * 8;
        const short8 a0 = ldb8(qb), a1 = ldb8(qb + 32), a2 = ldb8(qb + 64), a3 = ldb8(qb + 96);
        const bf16* kbp = K2c + ((size_t)(bh * 1024 + w * 256 + lo)) * 128 + hi * 8;
        short8 b0 = ldb8(kbp), b1 = ldb8(kbp + 32), b2 = ldb8(kbp + 64), b3 = ldb8(kbp + 96);
        const int even = !(lane & 1);
        for (int t = 0; t < 16; ++t) {
            const short8 c0f = b0, c1f = b1, c2f = b2, c3f = b3;
            if (t < 15) {
                kbp += 16 * 128;
                b0 = ldb8(kbp); b1 = ldb8(kbp + 32); b2 = ldb8(kbp + 64); b3 = ldb8(kbp + 96);
            }
            f32x4 acc = {0.f, 0.f, 0.f, 0.f};
            acc = MFMA16(a0, c0f, acc);
            acc = MFMA16(a1, c1f, acc);
            acc = MFMA16(a2, c2f, acc);
            acc = MFMA16(a3, c3f, acc);
            // pack column-pairs via lane^1 exchange, write 2 dwords/lane
            int lo16[4], pr[4];
            #pragma unroll
            for (int r = 0; r < 4; ++r) lo16[r] = ((int)acc[r]) & 0xFFFF;
            #pragma unroll
            for (int r = 0; r < 4; ++r) pr[r] = __shfl_xor(lo16[r], 1);
            const int cp = (w * 256 + t * 16 + lo) >> 1;
            if (even) {
                Sdw[(hi * 4 + 0) * 520 + cp] = (unsigned)(lo16[0] | (pr[0] << 16));
                Sdw[(hi * 4 + 1) * 520 + cp] = (unsigned)(lo16[1] | (pr[1] << 16));
            } else {
                Sdw[(hi * 4 + 2) * 520 + cp] = (unsigned)(pr[2] | (lo16[2] << 16));
                Sdw[(hi * 4 + 3) * 520 + cp] = (unsigned)(pr[3] | (lo16[3] << 16));
            }
        }
    }
    __syncthreads();

    // ---- Phase 2: max / sum — identical column order + shuffle tree ----
    const int row = tid >> 4, q = tid & 15;
    const short* Ss = (const short*)Sdw;
    int mi = -(1 << 20);
    #pragma unroll 8
    for (int j = 0; j < 64; ++j) mi = max(mi, (int)Ss[row * 1040 + q + (j << 4)]);
    mi = max(mi, __shfl_xor(mi, 1));
    mi = max(mi, __shfl_xor(mi, 2));
    mi = max(mi, __shfl_xor(mi, 4));
    mi = max(mi, __shfl_xor(mi, 8));
    float sum = 0.f;
    #pragma unroll 8
    for (int j = 0; j < 64; ++j) {
        const int siv = Ss[row * 1040 + q + (j << 4)];
        sum += expf(0.125f * (float)(siv - mi));     // == expf(0.125s - 0.125m) exactly
    }
    sum += __shfl_xor(sum, 1);
    sum += __shfl_xor(sum, 2);
    sum += __shfl_xor(sum, 4);
    sum += __shfl_xor(sum, 8);

    // ---- Phase 3: attn IF; P1 packed to registers, spikes to a 64-bit mask ----
    unsigned p1r[32];
    unsigned long long spb = 0ull;
    const size_t gRow = ((size_t)bh * 1024 + (n0 + row)) * 1024;
    #pragma unroll
    for (int j = 0; j < 8; ++j) {
        const int kb = q + 16 * j;                 // 8-col block, cols kb*8..+7
        const uint4 sw = *reinterpret_cast<const uint4*>(Sc + row * 2080 + kb * 16);
        const float4 vm0 = *reinterpret_cast<const float4*>(avm + gRow + kb * 8);
        const float4 vm1 = *reinterpret_cast<const float4*>(avm + gRow + kb * 8 + 4);
        const int4  ac0 = *reinterpret_cast<const int4*>(aac + gRow + kb * 8);
        const int4  ac1 = *reinterpret_cast<const int4*>(aac + gRow + kb * 8 + 4);
        const int s[8] = {(short)sw.x, (short)(sw.x >> 16), (short)sw.y, (short)(sw.y >> 16),
                          (short)sw.z, (short)(sw.z >> 16), (short)sw.w, (short)(sw.w >> 16)};
        const float vmr[8] = {vm0.x, vm0.y, vm0.z, vm0.w, vm1.x, vm1.y, vm1.z, vm1.w};
        const int   aar[8] = {ac0.x, ac0.y, ac0.z, ac0.w, ac1.x, ac1.y, ac1.z, ac1.w};
        unsigned hh[8];
        #pragma unroll
        for (int i = 0; i < 8; ++i) {
            const float e  = expf(0.125f * (float)(s[i] - mi));
            const float p7 = (e / sum) * 7.0f;
            const float v_ = (vmr[i] + 0.2f) + p7;   // v_ > 0 always (avm>=0)
            const int sp = ((v_ >= 1.0f) && (aar[i] < 7)) ? 1 : 0;
            hh[i] = bfu((float)(aar[i] + sp));
            spb |= ((unsigned long long)sp) << (8 * j + i);
        }
        p1r[4 * j + 0] = hh[0] | (hh[1] << 16);
        p1r[4 * j + 1] = hh[2] | (hh[3] << 16);
        p1r[4 * j + 2] = hh[4] | (hh[5] << 16);
        p1r[4 * j + 3] = hh[6] | (hh[7] << 16);
    }
    __syncthreads();   // all S16 reads done before P overlay

    // ---- Write P1 (bf16, XOR-swizzled 16B blocks) ----
    const int rsw = row & 7;
    #pragma unroll
    for (int j = 0; j < 8; ++j) {
        const int kbs = (q + 16 * j) ^ rsw;
        *reinterpret_cast<uint4*>(Sc + row * 2080 + kbs * 16) =
            uint4{p1r[4 * j], p1r[4 * j + 1], p1r[4 * j + 2], p1r[4 * j + 3]};
    }
    __syncthreads();

    // ---- PV pass A: acc = P1 @ Vs (exact int MFMA) ----
    const int d0 = w * 16;
    f32x4 acc = {0.f, 0.f, 0.f, 0.f};
    {
        const bf16* vs = VsT + ((size_t)(bh * 64 + d0 + lo)) * 1024 + hi * 8;
        short8 nv = ldb8(vs);
        for (int t = 0; t < 32; ++t) {
            const short8 cv = nv;
            if (t < 31) nv = ldb8(vs + (t + 1) * 32);
            const int kbs = (4 * t + hi) ^ (lo & 7);
            const short8 af = *reinterpret_cast<const short8*>(Sc + lo * 2080 + kbs * 16);
            acc = MFMA16(af, cv, acc);
        }
    }
    __syncthreads();   // pass-A reads done before P2 overwrite

    // ---- Write P2 = spikes (bf16 0/1 from the bit mask) ----
    #pragma unroll
    for (int j = 0; j < 8; ++j) {
        unsigned hh[8];
        #pragma unroll
        for (int i = 0; i < 8; ++i)
            hh[i] = ((spb >> (8 * j + i)) & 1ull) ? 0x3F80u : 0u;
        const int kbs = (q + 16 * j) ^ rsw;
        *reinterpret_cast<uint4*>(Sc + row * 2080 + kbs * 16) =
            uint4{hh[0] | (hh[1] << 16), hh[2] | (hh[3] << 16),
                  hh[4] | (hh[5] << 16), hh[6] | (hh[7] << 16)};
    }
    __syncthreads();

    // ---- PV pass B: acc += P2 @ Va; after-attn IF; write O2 ----
    {
        const bf16* va = VaT + ((size_t)(bh * 64 + d0 + lo)) * 1024 + hi * 8;
        short8 nv = ldb8(va);
        for (int t = 0; t < 32; ++t) {
            const short8 cv = nv;
            if (t < 31) nv = ldb8(va + (t + 1) * 32);
            const int kbs = (4 * t + hi) ^ (lo & 7);
            const short8 af = *reinterpret_cast<const short8*>(Sc + lo * 2080 + kbs * 16);
            acc = MFMA16(af, cv, acc);
        }
    }
    #pragma unroll
    for (int r = 0; r < 4; ++r) {
        const int n = n0 + hi * 4 + r;
        const float o = acc[r];                 // exact integer
        const float o2 = (o >= 0.5f ? 1.f : 0.f) - (o < -0.5f ? 1.f : 0.f);
        O2[((size_t)(bb * 1024 + n)) * 512 + h * 64 + d0 + lo] = __float2bfloat16(o2);
    }
}

// -------------------------------------------------------------------------
// Kernel 3: Y = O2 @ Wp^T + b_proj, f32 out. Same per-output MFMA chain as
// rounds 2-4 (bit-identical); 4x more blocks for latency hiding.
// -------------------------------------------------------------------------
__global__ __launch_bounds__(256) void k_proj(
    const bf16* __restrict__ O2, const bf16* __restrict__ W, const float* __restrict__ bias,
    float* __restrict__ Y)
{
    const int w = threadIdx.x >> 6, lane = threadIdx.x & 63;
    const int lo = lane & 15, hi = lane >> 4;
    const int r0 = blockIdx.y * 16;
    const int c0 = blockIdx.x * 64 + w * 16;

    f32x4 acc = {0.f, 0.f, 0.f, 0.f};
    const bf16* op = O2 + (size_t)(r0 + lo) * 512 + hi * 8;
    const bf16* bp = W + (size_t)(c0 + lo) * 512 + hi * 8;
    #pragma unroll 4
    for (int kb = 0; kb < 16; ++kb)
        acc = MFMA16(ldb8(op + kb * 32), ldb8(bp + kb * 32), acc);

    const int col = c0 + lo;
    const float bcol = bias[col];
    #pragma unroll
    for (int r = 0; r < 4; ++r) {
        const int row = r0 + hi * 4 + r;
        Y[(size_t)row * 512 + col] = acc[r] + bcol;
    }
}

// -------------------------------------------------------------------------
extern "C" void kernel_launch(void* const* d_in, const int* in_sizes, int n_in,
                              void* d_out, int out_size, void* d_ws, size_t ws_size,
                              hipStream_t stream)
{
    const float* x     = (const float*)d_in[0];
    const float* wqkv  = (const float*)d_in[1];
    const float* bqkv  = (const float*)d_in[2];
    const float* wproj = (const float*)d_in[3];
    const float* bproj = (const float*)d_in[4];
    const float* qvm   = (const float*)d_in[5];
    const float* kvm   = (const float*)d_in[6];
    const float* vvm   = (const float*)d_in[7];
    const float* avm   = (const float*)d_in[8];
    const int*   qac   = (const int*)d_in[9];
    const int*   kac   = (const int*)d_in[10];
    const int*   vac   = (const int*)d_in[11];
    const int*   aac   = (const int*)d_in[12];

    char* p = (char*)d_ws;
    bf16* Q2  = (bf16*)p; p += (size_t)32 * 1024 * 128 * 2;   // 8 MB  [bh][n][128]
    bf16* K2c = (bf16*)p; p += (size_t)32 * 1024 * 128 * 2;   // 8 MB  [bh][m][128]
    bf16* VsT = (bf16*)p; p += (size_t)32 * 64 * 1024 * 2;    // 4 MB  [bh][d][m]
    bf16* VaT = (bf16*)p; p += (size_t)32 * 64 * 1024 * 2;    // 4 MB
    bf16* O2  = (bf16*)p; p += (size_t)4096 * 512 * 2;        // 4 MB  [B*N][C]
    bf16* Wp  = (bf16*)p; p += (size_t)512 * 512 * 2;         // 0.5MB w_proj bf16

    k_cast<<<dim3(256), 256, 0, stream>>>(wproj, Wp, 512 * 512);
    k_qkv_f32<<<dim3(24, 64), 256, 0, stream>>>(x, wqkv, bqkv, qvm, kvm, vvm,
                                                qac, kac, vac, Q2, K2c, VsT, VaT);
    k_attn<<<dim3(64, 8, 4), 256, 0, stream>>>(Q2, K2c, avm, aac, VsT, VaT, O2);
    k_proj<<<dim3(8, 256), 256, 0, stream>>>(O2, Wp, bproj, (float*)d_out);
}